// Round 1
// baseline (91.733 us; speedup 1.0000x reference)
//
#include <hip/hip_runtime.h>

// out[b,o] = sum_{r<4} x[b, 4o+r] * w[4o+r]  +  sum_{r<4} bias[4o+r]
// B=16384, N_IN=4096, N_OUT=1024, ratio=4.
// Flat: x4[idx] (float4) pairs with out[idx], idx = b*1024 + o; w4[o], b4[o].

constexpr int N_OUT_C = 1024;

__global__ __launch_bounds__(256) void sparse_layer_kernel(
    const float4* __restrict__ x4,    // B*N_OUT float4s (= x viewed as [B*N_OUT][4])
    const float4* __restrict__ w4,    // N_OUT float4s
    const float4* __restrict__ b4,    // N_OUT float4s
    float4* __restrict__ out4,        // (B*N_OUT)/4 float4s
    int total4)
{
    int tid = blockIdx.x * blockDim.x + threadIdx.x;
    int stride = gridDim.x * blockDim.x;
    for (int t = tid; t < total4; t += stride) {
        int base = t * 4;                  // first output index of this thread's float4
        int o = base & (N_OUT_C - 1);      // column group base (stays within row: 1024%4==0)
        float r[4];
        #pragma unroll
        for (int j = 0; j < 4; ++j) {
            float4 xv = x4[base + j];
            float4 wv = w4[o + j];
            float4 bv = b4[o + j];
            float bsum = (bv.x + bv.y) + (bv.z + bv.w);
            r[j] = xv.x * wv.x + xv.y * wv.y + xv.z * wv.z + xv.w * wv.w + bsum;
        }
        out4[t] = make_float4(r[0], r[1], r[2], r[3]);
    }
}

extern "C" void kernel_launch(void* const* d_in, const int* in_sizes, int n_in,
                              void* d_out, int out_size, void* d_ws, size_t ws_size,
                              hipStream_t stream) {
    const float4* x4 = (const float4*)d_in[0];   // x: (16384, 4096) f32
    const float4* w4 = (const float4*)d_in[1];   // weights: (4096,) f32
    const float4* b4 = (const float4*)d_in[2];   // bias: (4096,) f32
    // d_in[3] is n_out scalar (1024) — hardcoded as N_OUT_C.
    float4* out4 = (float4*)d_out;               // out: (16384, 1024) f32

    int total4 = out_size / 4;                   // 4,194,304
    int block = 256;
    int grid = 2048;                             // grid-stride, ~8 iters/thread
    sparse_layer_kernel<<<grid, block, 0, stream>>>(x4, w4, b4, out4, total4);
}

// Round 2
// 52.179 us; speedup vs baseline: 1.7581x; 1.7581x over previous
//
#include <hip/hip_runtime.h>

// out[b,o] = sum_{r<4} x[b, 4o+r] * w[4o+r]  +  sum_{r<4} bias[4o+r]
// B=16384, N_IN=4096, N_OUT=1024, ratio=4.
// Flat over t = b*1024 + o: out[t] = dot(x4[t], w4[t&1023]) + bsum[t&1023].
//
// Coalescing: consecutive lanes read consecutive float4s of x (16B/lane,
// 1 KiB per wave load instruction) and write consecutive floats of out.
// stride is a multiple of 1024, so each thread's column group o = tid&1023
// is loop-invariant -> w/bias live in registers across all 32 iterations.

constexpr int N_OUT_C = 1024;

__global__ __launch_bounds__(256) void sparse_layer_kernel(
    const float4* __restrict__ x4,    // B*N_OUT float4s (x viewed as [B*N_OUT][4])
    const float4* __restrict__ w4,    // N_OUT float4s
    const float4* __restrict__ b4,    // N_OUT float4s
    float* __restrict__ out,          // B*N_OUT floats
    int total)
{
    int tid = blockIdx.x * blockDim.x + threadIdx.x;
    int stride = gridDim.x * blockDim.x;   // 524288 = 512*1024 -> o invariant

    int o = tid & (N_OUT_C - 1);
    float4 wv = w4[o];
    float4 bv = b4[o];
    float bsum = (bv.x + bv.y) + (bv.z + bv.w);

    for (int t = tid; t < total; t += stride) {
        float4 xv = x4[t];
        float r = xv.x * wv.x + xv.y * wv.y + xv.z * wv.z + xv.w * wv.w + bsum;
        __builtin_nontemporal_store(r, out + t);
    }
}

extern "C" void kernel_launch(void* const* d_in, const int* in_sizes, int n_in,
                              void* d_out, int out_size, void* d_ws, size_t ws_size,
                              hipStream_t stream) {
    const float4* x4 = (const float4*)d_in[0];   // x: (16384, 4096) f32
    const float4* w4 = (const float4*)d_in[1];   // weights: (4096,) f32
    const float4* b4 = (const float4*)d_in[2];   // bias: (4096,) f32
    float* outp = (float*)d_out;                 // out: (16384, 1024) f32

    int total = out_size;                        // 16,777,216 outputs
    int block = 256;
    int grid = 2048;                             // 524288 threads, 32 iters each
    sparse_layer_kernel<<<grid, block, 0, stream>>>(x4, w4, b4, outp, total);
}